// Round 7
// baseline (352.826 us; speedup 1.0000x reference)
//
#include <hip/hip_runtime.h>
#include <hip/hip_fp8.h>
#include <math.h>

#define N_NODES 100000
#define N_EDGES 1600000
#define N_GRAPHS 256
#define H 128
#define EPS_BN 1e-5f
#define ELLW 64

// sort-based build params (round-2 proven pipeline)
#define PSZ 256
#define PSH 8
#define P_PART 391                    // ceil(100000/256)
#define BLD_NBLK 200
#define EPT 32
#define EPB_A (256 * EPT)

typedef unsigned int uint;
typedef unsigned short ushort;
typedef __attribute__((ext_vector_type(8))) short bf16x8;
typedef __attribute__((ext_vector_type(4))) float f32x4;
typedef __attribute__((ext_vector_type(2))) float f32x2;
typedef __attribute__((ext_vector_type(4))) int i32x4;
typedef __attribute__((ext_vector_type(2))) int i32x2;

// ---- bf16 helpers ----
__device__ __forceinline__ uint f2bf_bits(float x) {
    uint u = __float_as_uint(x);
    return (u + 0x7fffu + ((u >> 16) & 1u)) >> 16;
}
__device__ __forceinline__ uint pack_bf2(float a, float b) {
    return f2bf_bits(a) | (f2bf_bits(b) << 16);
}

// ---- fp8 helpers ----
__device__ __forceinline__ unsigned char f32_to_fp8(float x) {
#if __has_builtin(__builtin_amdgcn_cvt_pk_fp8_f32)
    int v = __builtin_amdgcn_cvt_pk_fp8_f32(x, 0.0f, 0, false);
    return (unsigned char)(v & 0xff);
#else
    __hip_fp8_e4m3 q(x);
    return (unsigned char)q.__x;
#endif
}
__device__ __forceinline__ f32x4 fp8x4_to_f32x4(uint v) {
    f32x4 r;
#if __has_builtin(__builtin_amdgcn_cvt_pk_f32_fp8)
    f32x2 lo = __builtin_amdgcn_cvt_pk_f32_fp8((int)v, false);
    f32x2 hi = __builtin_amdgcn_cvt_pk_f32_fp8((int)v, true);
    r.x = lo.x; r.y = lo.y; r.z = hi.x; r.w = hi.y;
#else
    __hip_fp8_e4m3 a, b, c, d;
    a.__x = (unsigned char)(v & 0xff);
    b.__x = (unsigned char)((v >> 8) & 0xff);
    c.__x = (unsigned char)((v >> 16) & 0xff);
    d.__x = (unsigned char)((v >> 24) & 0xff);
    r.x = (float)a; r.y = (float)b; r.z = (float)c; r.w = (float)d;
#endif
    return r;
}

// ====== fused: histogram (0..199) + graph bounds (200..591) + W packs
//        (592..607) + Gz zero + sentinel-row zeros (608) ====================
__global__ __launch_bounds__(256) void k_hist(const int* __restrict__ dst,
                                              int* __restrict__ hist,
                                              const int* __restrict__ batch,
                                              int* __restrict__ gstart,
                                              const float* __restrict__ W2,
                                              ushort* __restrict__ Wpk2,
                                              const float* __restrict__ W3,
                                              ushort* __restrict__ Wpk3,
                                              float* __restrict__ Gz,
                                              uint* __restrict__ HfApad,
                                              uint* __restrict__ HfBpad) {
    __shared__ int h[P_PART];
    int b = blockIdx.x;
    if (b < BLD_NBLK) {
        for (int i = threadIdx.x; i < P_PART; i += 256) h[i] = 0;
        __syncthreads();
        int base = b * EPB_A + threadIdx.x * EPT;
        #pragma unroll
        for (int j = 0; j < EPT / 4; j++) {
            int e = base + j * 4;
            if (e + 4 <= N_EDGES) {
                i32x4 d = __builtin_nontemporal_load((const i32x4*)&dst[e]);
                atomicAdd(&h[d.x >> PSH], 1);
                atomicAdd(&h[d.y >> PSH], 1);
                atomicAdd(&h[d.z >> PSH], 1);
                atomicAdd(&h[d.w >> PSH], 1);
            }
        }
        __syncthreads();
        for (int i = threadIdx.x; i < P_PART; i += 256)
            hist[b * P_PART + i] = h[i];
        return;
    }
    if (b < 592) {
        int n = (b - 200) * 256 + threadIdx.x;
        if (n >= N_NODES) return;
        int g = batch[n];
        int gp = (n == 0) ? -1 : batch[n - 1];
        for (int gr = gp + 1; gr <= g; gr++) gstart[gr] = n;
        if (n == N_NODES - 1) {
            for (int gr = g + 1; gr <= N_GRAPHS; gr++) gstart[gr] = N_NODES;
        }
        return;
    }
    if (b >= 608) {
        if (threadIdx.x < N_GRAPHS) Gz[threadIdx.x] = 0.0f;
        if (threadIdx.x < 32) HfApad[threadIdx.x] = 0u;   // zero sentinel rows
        if (threadIdx.x < 32) HfBpad[threadIdx.x] = 0u;   // (HfBpad is past ebuf)
        return;
    }
    const float* W = (b < 600) ? W2 : W3;
    ushort* Wpk = (b < 600) ? Wpk2 : Wpk3;
    int t = ((b < 600) ? (b - 592) : (b - 600)) * 256 + threadIdx.x;  // 0..2047
    int lane = t & 63, nt = (t >> 6) & 7, kt = t >> 9;
    int n = nt * 16 + (lane & 15);
    int kbase = kt * 32 + (lane >> 4) * 8;
    ushort v[8];
    #pragma unroll
    for (int j = 0; j < 8; j++)
        v[j] = (ushort)f2bf_bits(W[(size_t)(kbase + j) * H + n]);
    uint4 pk;
    pk.x = (uint)v[0] | ((uint)v[1] << 16);
    pk.y = (uint)v[2] | ((uint)v[3] << 16);
    pk.z = (uint)v[4] | ((uint)v[5] << 16);
    pk.w = (uint)v[6] | ((uint)v[7] << 16);
    *(uint4*)&Wpk[(size_t)t * 8] = pk;
}

// ---- scan A ----------------------------------------------------------------
__global__ __launch_bounds__(256) void k_scan_a(const int* __restrict__ hist,
                                                int* __restrict__ offs,
                                                int* __restrict__ tot) {
    __shared__ int lds[256];
    int p = blockIdx.x;
    int t = threadIdx.x;
    int v = (t < BLD_NBLK) ? hist[t * P_PART + p] : 0;
    lds[t] = v;
    __syncthreads();
    for (int off = 1; off < 256; off <<= 1) {
        int tmp = (t >= off) ? lds[t - off] : 0;
        __syncthreads();
        lds[t] += tmp;
        __syncthreads();
    }
    if (t < BLD_NBLK) offs[t * P_PART + p] = lds[t] - v;
    if (t == 255) tot[p] = lds[255];
}

// ---- scan B ----------------------------------------------------------------
__global__ void k_scan_b(const int* __restrict__ tot, int* __restrict__ parr) {
    __shared__ int lds[512];
    int p = threadIdx.x;
    int v = (p < P_PART) ? tot[p] : 0;
    lds[p] = v;
    __syncthreads();
    for (int off = 1; off < 512; off <<= 1) {
        int tmp = (p >= off) ? lds[p - off] : 0;
        __syncthreads();
        lds[p] += tmp;
        __syncthreads();
    }
    if (p < P_PART) parr[p] = lds[p] - v;
    if (p == 0) parr[P_PART] = N_EDGES;
}

__global__ __launch_bounds__(256) void k_scatter(const int* __restrict__ src,
                                                 const int* __restrict__ dst,
                                                 const int* __restrict__ offs,
                                                 const int* __restrict__ parr,
                                                 i32x2* __restrict__ ebuf) {
    __shared__ int lofs[P_PART];
    for (int i = threadIdx.x; i < P_PART; i += 256)
        lofs[i] = offs[blockIdx.x * P_PART + i] + parr[i];
    __syncthreads();
    int base = blockIdx.x * EPB_A + threadIdx.x * EPT;
    #pragma unroll
    for (int j = 0; j < EPT / 4; j++) {
        int e = base + j * 4;
        if (e + 4 <= N_EDGES) {
            i32x4 d = __builtin_nontemporal_load((const i32x4*)&dst[e]);
            i32x4 s = __builtin_nontemporal_load((const i32x4*)&src[e]);
            #pragma unroll
            for (int k = 0; k < 4; k++) {
                int dk = (k == 0) ? d.x : (k == 1) ? d.y : (k == 2) ? d.z : d.w;
                int sk = (k == 0) ? s.x : (k == 1) ? s.y : (k == 2) ? s.z : s.w;
                int pos = atomicAdd(&lofs[dk >> PSH], 1);
                i32x2 sd; sd.x = sk; sd.y = dk;
                ebuf[pos] = sd;
            }
        }
    }
}

// build ELL + pad each row to a multiple of 16 with the zero-sentinel index
__global__ __launch_bounds__(256) void k_build(const i32x2* __restrict__ ebuf,
                                               const int* __restrict__ parr,
                                               int* __restrict__ cnt,
                                               int* __restrict__ ell) {
    __shared__ int lc[PSZ];
    int p = blockIdx.x;
    for (int i = threadIdx.x; i < PSZ; i += 256) lc[i] = 0;
    __syncthreads();
    int e0 = parr[p], e1 = parr[p + 1];
    for (int i = e0 + threadIdx.x; i < e1; i += 256) {
        i32x2 sd = ebuf[i];
        int d = sd.y;
        int slot = atomicAdd(&lc[d & (PSZ - 1)], 1);
        if (slot < ELLW) ell[(size_t)d * ELLW + slot] = sd.x;
    }
    __syncthreads();
    int nb = p * PSZ;
    for (int i = threadIdx.x; i < PSZ; i += 256) {
        int n = nb + i;
        if (n < N_NODES) {
            int c = lc[i];
            cnt[n] = c;
            int cc = (c < ELLW) ? c : ELLW;
            int cp = (cc + 15) & ~15;
            if (cp > ELLW) cp = ELLW;
            for (int slot = cc; slot < cp; slot++)
                ell[(size_t)n * ELLW + slot] = N_NODES;   // sentinel (zero row)
        }
    }
}

// ---------------- fused layer 1: 4 nodes per wave, 16 lanes per node ---------
__global__ __launch_bounds__(256) void k_layer1(
    const float* __restrict__ x, const int* __restrict__ cnt,
    const int* __restrict__ ell, const float* __restrict__ W1,
    const float* __restrict__ gamma, const float* __restrict__ beta,
    const float* __restrict__ mean, const float* __restrict__ var,
    uint* __restrict__ Hf8) {
    __shared__ float scs[128], shs[128];
    int tid = threadIdx.x;
    if (tid < 128) {
        float sc = gamma[tid] * rsqrtf(var[tid] + EPS_BN);
        scs[tid] = sc;
        shs[tid] = beta[tid] - mean[tid] * sc;
    }
    __syncthreads();
    int lane = tid & 63, wave = tid >> 6;
    int sub = lane >> 4, m = lane & 15;
    int n = blockIdx.x * 16 + wave * 4 + sub;
    if (n >= N_NODES) return;
    int cn = cnt[n]; if (cn > ELLW) cn = ELLW;
    const int* row = &ell[(size_t)n * ELLW];
    float4 acc = {0.f, 0.f, 0.f, 0.f};
    for (int e = m; e < cn; e += 16) {
        float4 v = *(const float4*)&x[(size_t)row[e] * 4];
        acc.x += v.x; acc.y += v.y; acc.z += v.z; acc.w += v.w;
    }
    #pragma unroll
    for (int off = 8; off > 0; off >>= 1) {
        acc.x += __shfl_down(acc.x, off, 16);
        acc.y += __shfl_down(acc.y, off, 16);
        acc.z += __shfl_down(acc.z, off, 16);
        acc.w += __shfl_down(acc.w, off, 16);
    }
    int src = lane & 48;
    float4 xs = *(const float4*)&x[(size_t)n * 4];
    float uu[4];
    uu[0] = __shfl(acc.x, src, 64) + xs.x;
    uu[1] = __shfl(acc.y, src, 64) + xs.y;
    uu[2] = __shfl(acc.z, src, 64) + xs.z;
    uu[3] = __shfl(acc.w, src, 64) + xs.w;
    int j0 = m * 8;
    float z[8] = {0.f, 0.f, 0.f, 0.f, 0.f, 0.f, 0.f, 0.f};
    #pragma unroll
    for (int k = 0; k < 4; k++) {
        float4 wa = *(const float4*)&W1[k * H + j0];
        float4 wb = *(const float4*)&W1[k * H + j0 + 4];
        z[0] += uu[k] * wa.x; z[1] += uu[k] * wa.y;
        z[2] += uu[k] * wa.z; z[3] += uu[k] * wa.w;
        z[4] += uu[k] * wb.x; z[5] += uu[k] * wb.y;
        z[6] += uu[k] * wb.z; z[7] += uu[k] * wb.w;
    }
    #pragma unroll
    for (int i = 0; i < 8; i++)
        z[i] = fmaxf(z[i] * scs[j0 + i] + shs[j0 + i], 0.0f);
    uint2 q;
    q.x = (uint)f32_to_fp8(z[0]) | ((uint)f32_to_fp8(z[1]) << 8)
        | ((uint)f32_to_fp8(z[2]) << 16) | ((uint)f32_to_fp8(z[3]) << 24);
    q.y = (uint)f32_to_fp8(z[4]) | ((uint)f32_to_fp8(z[5]) << 8)
        | ((uint)f32_to_fp8(z[6]) << 16) | ((uint)f32_to_fp8(z[7]) << 24);
    *(uint2*)&Hf8[(size_t)n * 32 + m * 2] = q;
}

// ---------------- fused aggregate (round-2 per-wave shape) + MFMA epilogue ---
// 512 threads = 8 waves = 8 nodes per block; each wave aggregates ONE node
// exactly as round-2's k_aggr128 (100000 independent node-waves chip-wide),
// writes its bf16 row to LDS; after one barrier, wave 0 alone runs the
// 32-MFMA GEMM on the 16-row tile (rows 8..15 read garbage LDS -- harmless:
// C-row i depends only on A-row i; only rows 0..7 are stored/pooled).
// mode 1 = BN+ReLU -> fp8 Hout; mode 2 = BN+ReLU -> fused graph pooling.
__global__ __launch_bounds__(512) void k_aggr_gemm(
    const uint* __restrict__ Hin, const int* __restrict__ cnt,
    const int* __restrict__ ell, const uint* __restrict__ Wpk,
    const float* __restrict__ gamma, const float* __restrict__ beta,
    const float* __restrict__ mean, const float* __restrict__ var,
    unsigned char* __restrict__ Hout,
    const int* __restrict__ batch, const float* __restrict__ Wfc,
    float* __restrict__ Gz, int mode) {
    __shared__ uint lds_u[16 * 68];
    int tid = threadIdx.x;
    int wid = tid >> 6, lane = tid & 63;
    int n0 = blockIdx.x * 8;
    int n = n0 + wid;                      // grid is exact: n < N_NODES always

    // ---- per-wave aggregation (round-2 exact) ----
    int g = lane >> 4, c8 = lane & 15;
    const int* row = &ell[(size_t)n * ELLW];
    i32x4 id = *(const i32x4*)(row + 4 * g);
    uint2 sp = {0u, 0u};
    if (g == 0) sp = *(const uint2*)&Hin[(size_t)n * 32 + c8 * 2];
    int cn = cnt[n]; if (cn > ELLW) cn = ELLW;
    int cnp = (cn + 15) & ~15; if (cnp > ELLW) cnp = ELLW;

    f32x4 A = {0.f, 0.f, 0.f, 0.f};
    f32x4 B = {0.f, 0.f, 0.f, 0.f};
    for (int e = 0; e < cnp; e += 16) {
        i32x4 idn = id;
        if (e + 16 < cnp) idn = *(const i32x4*)(row + e + 16 + 4 * g);
        int s0 = id.x, s1 = id.y, s2 = id.z, s3 = id.w;
        uint2 p0 = *(const uint2*)&Hin[(size_t)s0 * 32 + c8 * 2];
        uint2 p1 = *(const uint2*)&Hin[(size_t)s1 * 32 + c8 * 2];
        uint2 p2 = *(const uint2*)&Hin[(size_t)s2 * 32 + c8 * 2];
        uint2 p3 = *(const uint2*)&Hin[(size_t)s3 * 32 + c8 * 2];
        f32x4 l0 = fp8x4_to_f32x4(p0.x), h0 = fp8x4_to_f32x4(p0.y);
        f32x4 l1 = fp8x4_to_f32x4(p1.x), h1 = fp8x4_to_f32x4(p1.y);
        f32x4 l2 = fp8x4_to_f32x4(p2.x), h2 = fp8x4_to_f32x4(p2.y);
        f32x4 l3 = fp8x4_to_f32x4(p3.x), h3 = fp8x4_to_f32x4(p3.y);
        A += (l0 + l1) + (l2 + l3);
        B += (h0 + h1) + (h2 + h3);
        id = idn;
    }
    if (g == 0) {
        A += fp8x4_to_f32x4(sp.x);
        B += fp8x4_to_f32x4(sp.y);
    }
    #pragma unroll
    for (int off = 32; off >= 16; off >>= 1) {
        A.x += __shfl_down(A.x, off, 64);
        A.y += __shfl_down(A.y, off, 64);
        A.z += __shfl_down(A.z, off, 64);
        A.w += __shfl_down(A.w, off, 64);
        B.x += __shfl_down(B.x, off, 64);
        B.y += __shfl_down(B.y, off, 64);
        B.z += __shfl_down(B.z, off, 64);
        B.w += __shfl_down(B.w, off, 64);
    }
    if (g == 0) {
        uint4 ov;
        ov.x = pack_bf2(A.x, A.y);
        ov.y = pack_bf2(A.z, A.w);
        ov.z = pack_bf2(B.x, B.y);
        ov.w = pack_bf2(B.z, B.w);
        *(uint4*)&lds_u[wid * 68 + c8 * 4] = ov;
    }
    __syncthreads();
    if (wid != 0) return;

    // ---- GEMM epilogue by wave 0 (rows 0..7 valid) ----
    int m = lane & 15, quad = lane >> 4;
    bf16x8 a[4];
    #pragma unroll
    for (int kt = 0; kt < 4; kt++)
        a[kt] = *(const bf16x8*)&lds_u[m * 68 + kt * 16 + quad * 4];

    f32x4 acc[8];
    #pragma unroll
    for (int nt = 0; nt < 8; nt++) acc[nt] = (f32x4){0.f, 0.f, 0.f, 0.f};

    #pragma unroll
    for (int nt = 0; nt < 8; nt++) {
        #pragma unroll
        for (int kt = 0; kt < 4; kt++) {
            bf16x8 b = *(const bf16x8*)&Wpk[((size_t)(kt * 8 + nt) * 64 + lane) * 4];
            acc[nt] = __builtin_amdgcn_mfma_f32_16x16x32_bf16(a[kt], b, acc[nt], 0, 0, 0);
        }
    }

    if (mode == 1) {
        if (quad < 2) {
            #pragma unroll
            for (int nt = 0; nt < 8; nt++) {
                int col = nt * 16 + m;
                float sc = gamma[col] * rsqrtf(var[col] + EPS_BN);
                float sh = beta[col] - mean[col] * sc;
                #pragma unroll
                for (int r = 0; r < 4; r++) {
                    int rowi = n0 + quad * 4 + r;
                    float z = fmaxf(acc[nt][r] * sc + sh, 0.0f);
                    Hout[(size_t)rowi * 128 + col] = f32_to_fp8(z);
                }
            }
        }
    } else {
        float pr[4] = {0.f, 0.f, 0.f, 0.f};
        #pragma unroll
        for (int nt = 0; nt < 8; nt++) {
            int col = nt * 16 + m;
            float sc = gamma[col] * rsqrtf(var[col] + EPS_BN);
            float sh = beta[col] - mean[col] * sc;
            float wf = Wfc[col];
            #pragma unroll
            for (int r = 0; r < 4; r++) {
                float z = fmaxf(acc[nt][r] * sc + sh, 0.0f);
                pr[r] += z * wf;
            }
        }
        #pragma unroll
        for (int r = 0; r < 4; r++) {
            pr[r] += __shfl_down(pr[r], 8, 16);
            pr[r] += __shfl_down(pr[r], 4, 16);
            pr[r] += __shfl_down(pr[r], 2, 16);
            pr[r] += __shfl_down(pr[r], 1, 16);
        }
        if (m == 0 && quad < 2) {
            // this lane holds pooled dot-products for rows n0+quad*4 .. +3
            int base = n0 + quad * 4;
            int gprev = batch[base];
            float s = pr[0];
            #pragma unroll
            for (int r = 1; r < 4; r++) {
                int gg = batch[base + r];
                if (gg == gprev) s += pr[r];
                else { atomicAdd(&Gz[gprev], s); gprev = gg; s = pr[r]; }
            }
            atomicAdd(&Gz[gprev], s);
        }
    }
}

// ---------------- final: out[g] = sigmoid(Gz[g] / count) ---------------------
__global__ void k_fc(const float* __restrict__ Gz, const int* __restrict__ gstart,
                     float* __restrict__ out) {
    int g = threadIdx.x;
    if (g < N_GRAPHS) {
        int c = gstart[g + 1] - gstart[g];
        float z = Gz[g] / fmaxf((float)c, 1.0f);
        out[g] = 1.0f / (1.0f + expf(-z));
    }
}

extern "C" void kernel_launch(void* const* d_in, const int* in_sizes, int n_in,
                              void* d_out, int out_size, void* d_ws, size_t ws_size,
                              hipStream_t stream) {
    const float* x     = (const float*)d_in[0];
    const int*   ei    = (const int*)d_in[1];
    const int*   batch = (const int*)d_in[2];
    const float* W1    = (const float*)d_in[3];
    const float* g1    = (const float*)d_in[4];
    const float* b1    = (const float*)d_in[5];
    const float* m1    = (const float*)d_in[6];
    const float* v1    = (const float*)d_in[7];
    const float* W2    = (const float*)d_in[8];
    const float* g2    = (const float*)d_in[9];
    const float* b2    = (const float*)d_in[10];
    const float* m2    = (const float*)d_in[11];
    const float* v2    = (const float*)d_in[12];
    const float* W3    = (const float*)d_in[13];
    const float* g3    = (const float*)d_in[14];
    const float* b3    = (const float*)d_in[15];
    const float* m3    = (const float*)d_in[16];
    const float* v3    = (const float*)d_in[17];
    const float* Wfc   = (const float*)d_in[18];
    float* out = (float*)d_out;

    const int* srcp = ei;
    const int* dstp = ei + N_EDGES;

    // workspace carve
    // HfB region (N*32+32 uints = 12.8MB + 128B): doubles as ebuf during the
    // build (ebuf needs exactly 12.8MB), then becomes layer-2's fp8 output.
    uint* HfB  = (uint*)d_ws;
    uint* HfA  = HfB + (size_t)N_NODES * 32 + 32;
    int* cnt   = (int*)(HfA + (size_t)N_NODES * 32 + 32);
    int* ell   = cnt + N_NODES;                         // N*ELLW (25.6 MB)
    int* gstart = ell + (size_t)N_NODES * ELLW;         // pad 260
    ushort* Wpk2 = (ushort*)(gstart + 260);             // 16384 shorts
    ushort* Wpk3 = Wpk2 + 16384;                        // 16384 shorts
    int* hist  = (int*)(Wpk3 + 16384);                  // BLD_NBLK*P_PART
    int* offs  = hist + BLD_NBLK * P_PART;              // BLD_NBLK*P_PART
    int* parr  = offs + BLD_NBLK * P_PART;              // P_PART+1 (pad 400)
    int* tot   = parr + 400;                            // P_PART (pad 400)
    float* Gz  = (float*)(tot + 400);                   // N_GRAPHS
    i32x2* ebuf = (i32x2*)HfB;                          // N_EDGES int2 (12.8 MB)
    uint* HfApad = HfA + (size_t)N_NODES * 32;          // zero sentinel rows
    uint* HfBpad = HfB + (size_t)N_NODES * 32;          // (past ebuf's end)

    // sorted ELL build (no global atomics) + fused prep + Gz/sentinel zero
    k_hist<<<609, 256, 0, stream>>>(dstp, hist, batch, gstart, W2, Wpk2, W3, Wpk3,
                                    Gz, HfApad, HfBpad);
    k_scan_a<<<P_PART, 256, 0, stream>>>(hist, offs, tot);
    k_scan_b<<<1, 512, 0, stream>>>(tot, parr);
    k_scatter<<<BLD_NBLK, 256, 0, stream>>>(srcp, dstp, offs, parr, ebuf);
    k_build<<<P_PART, 256, 0, stream>>>(ebuf, parr, cnt, ell);

    // layer 1 (fused aggregate + MLP; fp8 mirror only) -> HfA
    k_layer1<<<(N_NODES + 15) / 16, 256, 0, stream>>>(
        x, cnt, ell, W1, g1, b1, m1, v1, HfA);
    // layer 2: fused aggregate + GEMM, HfA -> HfB (8 nodes / 512-thread block)
    k_aggr_gemm<<<N_NODES / 8, 512, 0, stream>>>(
        HfA, cnt, ell, (const uint*)Wpk2, g2, b2, m2, v2,
        (unsigned char*)HfB, batch, Wfc, Gz, 1);
    // layer 3: fused aggregate + GEMM + pooling, HfB -> Gz
    k_aggr_gemm<<<N_NODES / 8, 512, 0, stream>>>(
        HfB, cnt, ell, (const uint*)Wpk3, g3, b3, m3, v3,
        (unsigned char*)HfA, batch, Wfc, Gz, 2);
    // final sigmoid
    k_fc<<<1, 256, 0, stream>>>(Gz, gstart, out);
}

// Round 8
// 274.865 us; speedup vs baseline: 1.2836x; 1.2836x over previous
//
#include <hip/hip_runtime.h>
#include <hip/hip_fp8.h>
#include <math.h>

#define N_NODES 100000
#define N_EDGES 1600000
#define N_GRAPHS 256
#define H 128
#define EPS_BN 1e-5f
#define ELLW 64

// sort-based build params (round-2 proven pipeline)
#define PSZ 256
#define PSH 8
#define P_PART 391                    // ceil(100000/256)
#define BLD_NBLK 200
#define EPT 32
#define EPB_A (256 * EPT)

typedef unsigned int uint;
typedef unsigned short ushort;
typedef __attribute__((ext_vector_type(8))) short bf16x8;
typedef __attribute__((ext_vector_type(4))) float f32x4;
typedef __attribute__((ext_vector_type(2))) float f32x2;
typedef __attribute__((ext_vector_type(4))) int i32x4;
typedef __attribute__((ext_vector_type(2))) int i32x2;

// ---- bf16 helpers ----
__device__ __forceinline__ uint f2bf_bits(float x) {
    uint u = __float_as_uint(x);
    return (u + 0x7fffu + ((u >> 16) & 1u)) >> 16;
}
__device__ __forceinline__ uint pack_bf2(float a, float b) {
    return f2bf_bits(a) | (f2bf_bits(b) << 16);
}

// ---- fp8 helpers ----
__device__ __forceinline__ unsigned char f32_to_fp8(float x) {
#if __has_builtin(__builtin_amdgcn_cvt_pk_fp8_f32)
    int v = __builtin_amdgcn_cvt_pk_fp8_f32(x, 0.0f, 0, false);
    return (unsigned char)(v & 0xff);
#else
    __hip_fp8_e4m3 q(x);
    return (unsigned char)q.__x;
#endif
}
__device__ __forceinline__ f32x4 fp8x4_to_f32x4(uint v) {
    f32x4 r;
#if __has_builtin(__builtin_amdgcn_cvt_pk_f32_fp8)
    f32x2 lo = __builtin_amdgcn_cvt_pk_f32_fp8((int)v, false);
    f32x2 hi = __builtin_amdgcn_cvt_pk_f32_fp8((int)v, true);
    r.x = lo.x; r.y = lo.y; r.z = hi.x; r.w = hi.y;
#else
    __hip_fp8_e4m3 a, b, c, d;
    a.__x = (unsigned char)(v & 0xff);
    b.__x = (unsigned char)((v >> 8) & 0xff);
    c.__x = (unsigned char)((v >> 16) & 0xff);
    d.__x = (unsigned char)((v >> 24) & 0xff);
    r.x = (float)a; r.y = (float)b; r.z = (float)c; r.w = (float)d;
#endif
    return r;
}

// ====== fused: histogram (0..199) + graph bounds (200..591) + W packs
//        (592..607) + Gz zero + Hf8 sentinel-row zero (608) ==================
__global__ __launch_bounds__(256) void k_hist(const int* __restrict__ dst,
                                              int* __restrict__ hist,
                                              const int* __restrict__ batch,
                                              int* __restrict__ gstart,
                                              const float* __restrict__ W2,
                                              ushort* __restrict__ Wpk2,
                                              const float* __restrict__ W3,
                                              ushort* __restrict__ Wpk3,
                                              float* __restrict__ Gz,
                                              uint* __restrict__ Hf8pad) {
    __shared__ int h[P_PART];
    int b = blockIdx.x;
    if (b < BLD_NBLK) {
        for (int i = threadIdx.x; i < P_PART; i += 256) h[i] = 0;
        __syncthreads();
        int base = b * EPB_A + threadIdx.x * EPT;
        #pragma unroll
        for (int j = 0; j < EPT / 4; j++) {
            int e = base + j * 4;
            if (e + 4 <= N_EDGES) {
                i32x4 d = __builtin_nontemporal_load((const i32x4*)&dst[e]);
                atomicAdd(&h[d.x >> PSH], 1);
                atomicAdd(&h[d.y >> PSH], 1);
                atomicAdd(&h[d.z >> PSH], 1);
                atomicAdd(&h[d.w >> PSH], 1);
            }
        }
        __syncthreads();
        for (int i = threadIdx.x; i < P_PART; i += 256)
            hist[b * P_PART + i] = h[i];
        return;
    }
    if (b < 592) {
        int n = (b - 200) * 256 + threadIdx.x;
        if (n >= N_NODES) return;
        int g = batch[n];
        int gp = (n == 0) ? -1 : batch[n - 1];
        for (int gr = gp + 1; gr <= g; gr++) gstart[gr] = n;
        if (n == N_NODES - 1) {
            for (int gr = g + 1; gr <= N_GRAPHS; gr++) gstart[gr] = N_NODES;
        }
        return;
    }
    if (b >= 608) {
        if (threadIdx.x < N_GRAPHS) Gz[threadIdx.x] = 0.0f;
        if (threadIdx.x < 32) Hf8pad[threadIdx.x] = 0u;   // zero sentinel row
        return;
    }
    const float* W = (b < 600) ? W2 : W3;
    ushort* Wpk = (b < 600) ? Wpk2 : Wpk3;
    int t = ((b < 600) ? (b - 592) : (b - 600)) * 256 + threadIdx.x;  // 0..2047
    int lane = t & 63, nt = (t >> 6) & 7, kt = t >> 9;
    int n = nt * 16 + (lane & 15);
    int kbase = kt * 32 + (lane >> 4) * 8;
    ushort v[8];
    #pragma unroll
    for (int j = 0; j < 8; j++)
        v[j] = (ushort)f2bf_bits(W[(size_t)(kbase + j) * H + n]);
    uint4 pk;
    pk.x = (uint)v[0] | ((uint)v[1] << 16);
    pk.y = (uint)v[2] | ((uint)v[3] << 16);
    pk.z = (uint)v[4] | ((uint)v[5] << 16);
    pk.w = (uint)v[6] | ((uint)v[7] << 16);
    *(uint4*)&Wpk[(size_t)t * 8] = pk;
}

// ---- scan A ----------------------------------------------------------------
__global__ __launch_bounds__(256) void k_scan_a(const int* __restrict__ hist,
                                                int* __restrict__ offs,
                                                int* __restrict__ tot) {
    __shared__ int lds[256];
    int p = blockIdx.x;
    int t = threadIdx.x;
    int v = (t < BLD_NBLK) ? hist[t * P_PART + p] : 0;
    lds[t] = v;
    __syncthreads();
    for (int off = 1; off < 256; off <<= 1) {
        int tmp = (t >= off) ? lds[t - off] : 0;
        __syncthreads();
        lds[t] += tmp;
        __syncthreads();
    }
    if (t < BLD_NBLK) offs[t * P_PART + p] = lds[t] - v;
    if (t == 255) tot[p] = lds[255];
}

// ---- scan B ----------------------------------------------------------------
__global__ void k_scan_b(const int* __restrict__ tot, int* __restrict__ parr) {
    __shared__ int lds[512];
    int p = threadIdx.x;
    int v = (p < P_PART) ? tot[p] : 0;
    lds[p] = v;
    __syncthreads();
    for (int off = 1; off < 512; off <<= 1) {
        int tmp = (p >= off) ? lds[p - off] : 0;
        __syncthreads();
        lds[p] += tmp;
        __syncthreads();
    }
    if (p < P_PART) parr[p] = lds[p] - v;
    if (p == 0) parr[P_PART] = N_EDGES;
}

__global__ __launch_bounds__(256) void k_scatter(const int* __restrict__ src,
                                                 const int* __restrict__ dst,
                                                 const int* __restrict__ offs,
                                                 const int* __restrict__ parr,
                                                 i32x2* __restrict__ ebuf) {
    __shared__ int lofs[P_PART];
    for (int i = threadIdx.x; i < P_PART; i += 256)
        lofs[i] = offs[blockIdx.x * P_PART + i] + parr[i];
    __syncthreads();
    int base = blockIdx.x * EPB_A + threadIdx.x * EPT;
    #pragma unroll
    for (int j = 0; j < EPT / 4; j++) {
        int e = base + j * 4;
        if (e + 4 <= N_EDGES) {
            i32x4 d = __builtin_nontemporal_load((const i32x4*)&dst[e]);
            i32x4 s = __builtin_nontemporal_load((const i32x4*)&src[e]);
            #pragma unroll
            for (int k = 0; k < 4; k++) {
                int dk = (k == 0) ? d.x : (k == 1) ? d.y : (k == 2) ? d.z : d.w;
                int sk = (k == 0) ? s.x : (k == 1) ? s.y : (k == 2) ? s.z : s.w;
                int pos = atomicAdd(&lofs[dk >> PSH], 1);
                i32x2 sd; sd.x = sk; sd.y = dk;
                ebuf[pos] = sd;
            }
        }
    }
}

// build ELL + pad each row to a multiple of 16 with the zero-sentinel index
__global__ __launch_bounds__(256) void k_build(const i32x2* __restrict__ ebuf,
                                               const int* __restrict__ parr,
                                               int* __restrict__ cnt,
                                               int* __restrict__ ell) {
    __shared__ int lc[PSZ];
    int p = blockIdx.x;
    for (int i = threadIdx.x; i < PSZ; i += 256) lc[i] = 0;
    __syncthreads();
    int e0 = parr[p], e1 = parr[p + 1];
    for (int i = e0 + threadIdx.x; i < e1; i += 256) {
        i32x2 sd = ebuf[i];
        int d = sd.y;
        int slot = atomicAdd(&lc[d & (PSZ - 1)], 1);
        if (slot < ELLW) ell[(size_t)d * ELLW + slot] = sd.x;
    }
    __syncthreads();
    int nb = p * PSZ;
    for (int i = threadIdx.x; i < PSZ; i += 256) {
        int n = nb + i;
        if (n < N_NODES) {
            int c = lc[i];
            cnt[n] = c;
            int cc = (c < ELLW) ? c : ELLW;
            int cp = (cc + 15) & ~15;
            if (cp > ELLW) cp = ELLW;
            for (int slot = cc; slot < cp; slot++)
                ell[(size_t)n * ELLW + slot] = N_NODES;   // sentinel (zero row)
        }
    }
}

// ---------------- fused layer 1: 4 nodes per wave, 16 lanes per node ---------
// writes only the fp8 mirror; 32-bit byte-offset addressing for x gathers
__global__ __launch_bounds__(256) void k_layer1(
    const float* __restrict__ x, const int* __restrict__ cnt,
    const int* __restrict__ ell, const float* __restrict__ W1,
    const float* __restrict__ gamma, const float* __restrict__ beta,
    const float* __restrict__ mean, const float* __restrict__ var,
    uint* __restrict__ Hf8) {
    __shared__ float scs[128], shs[128];
    int tid = threadIdx.x;
    if (tid < 128) {
        float sc = gamma[tid] * rsqrtf(var[tid] + EPS_BN);
        scs[tid] = sc;
        shs[tid] = beta[tid] - mean[tid] * sc;
    }
    __syncthreads();
    int lane = tid & 63, wave = tid >> 6;
    int sub = lane >> 4, m = lane & 15;
    int n = blockIdx.x * 16 + wave * 4 + sub;
    if (n >= N_NODES) return;
    int cn = cnt[n]; if (cn > ELLW) cn = ELLW;
    const int* row = &ell[(size_t)n * ELLW];
    const char* xb = (const char*)x;
    float4 acc = {0.f, 0.f, 0.f, 0.f};
    for (int e = m; e < cn; e += 16) {
        float4 v = *(const float4*)(xb + ((uint)row[e] << 4));
        acc.x += v.x; acc.y += v.y; acc.z += v.z; acc.w += v.w;
    }
    #pragma unroll
    for (int off = 8; off > 0; off >>= 1) {
        acc.x += __shfl_down(acc.x, off, 16);
        acc.y += __shfl_down(acc.y, off, 16);
        acc.z += __shfl_down(acc.z, off, 16);
        acc.w += __shfl_down(acc.w, off, 16);
    }
    int src = lane & 48;
    float4 xs = *(const float4*)(xb + ((uint)n << 4));
    float uu[4];
    uu[0] = __shfl(acc.x, src, 64) + xs.x;
    uu[1] = __shfl(acc.y, src, 64) + xs.y;
    uu[2] = __shfl(acc.z, src, 64) + xs.z;
    uu[3] = __shfl(acc.w, src, 64) + xs.w;
    int j0 = m * 8;
    float z[8] = {0.f, 0.f, 0.f, 0.f, 0.f, 0.f, 0.f, 0.f};
    #pragma unroll
    for (int k = 0; k < 4; k++) {
        float4 wa = *(const float4*)&W1[k * H + j0];
        float4 wb = *(const float4*)&W1[k * H + j0 + 4];
        z[0] += uu[k] * wa.x; z[1] += uu[k] * wa.y;
        z[2] += uu[k] * wa.z; z[3] += uu[k] * wa.w;
        z[4] += uu[k] * wb.x; z[5] += uu[k] * wb.y;
        z[6] += uu[k] * wb.z; z[7] += uu[k] * wb.w;
    }
    #pragma unroll
    for (int i = 0; i < 8; i++)
        z[i] = fmaxf(z[i] * scs[j0 + i] + shs[j0 + i], 0.0f);
    uint2 q;
    q.x = (uint)f32_to_fp8(z[0]) | ((uint)f32_to_fp8(z[1]) << 8)
        | ((uint)f32_to_fp8(z[2]) << 16) | ((uint)f32_to_fp8(z[3]) << 24);
    q.y = (uint)f32_to_fp8(z[4]) | ((uint)f32_to_fp8(z[5]) << 8)
        | ((uint)f32_to_fp8(z[6]) << 16) | ((uint)f32_to_fp8(z[7]) << 24);
    *(uint2*)&Hf8[(size_t)n * 32 + m * 2] = q;
}

// ---------------- H=128 aggregation, one node per wave ----------------------
// 16 lanes x uint2 cover the 128B row (4 rows per wave-instruction);
// 4 edge-groups (lane>>4) each gather 4 consecutive edges per 16-edge block.
// ELL rows padded to x16 with the zero-sentinel row -> uniform loop.
// 32-bit byte-offset addressing: base SGPR + (s<<7 | c8<<3) voffset.
__global__ __launch_bounds__(256) void k_aggr128(
    const uint* __restrict__ Hf8, const int* __restrict__ cnt,
    const int* __restrict__ ell, uint* __restrict__ Ubf) {
    int t = blockIdx.x * 256 + threadIdx.x;
    int n = t >> 6, lane = t & 63;
    if (n >= N_NODES) return;
    int g = lane >> 4, c8 = lane & 15;
    const int* row = &ell[(size_t)n * ELLW];
    const char* Hb = (const char*)Hf8;
    uint co = (uint)c8 << 3;                 // byte offset within row
    // issue independent loads first: first index block + self row
    i32x4 id = *(const i32x4*)(row + 4 * g);
    uint2 sp = {0u, 0u};
    if (g == 0) sp = *(const uint2*)(Hb + (((uint)n << 7) | co));
    int cn = cnt[n]; if (cn > ELLW) cn = ELLW;
    int cnp = (cn + 15) & ~15; if (cnp > ELLW) cnp = ELLW;

    f32x4 A = {0.f, 0.f, 0.f, 0.f};
    f32x4 B = {0.f, 0.f, 0.f, 0.f};
    for (int e = 0; e < cnp; e += 16) {
        i32x4 idn = id;
        if (e + 16 < cnp) idn = *(const i32x4*)(row + e + 16 + 4 * g);
        uint2 p0 = *(const uint2*)(Hb + (((uint)id.x << 7) | co));
        uint2 p1 = *(const uint2*)(Hb + (((uint)id.y << 7) | co));
        uint2 p2 = *(const uint2*)(Hb + (((uint)id.z << 7) | co));
        uint2 p3 = *(const uint2*)(Hb + (((uint)id.w << 7) | co));
        f32x4 l0 = fp8x4_to_f32x4(p0.x), h0 = fp8x4_to_f32x4(p0.y);
        f32x4 l1 = fp8x4_to_f32x4(p1.x), h1 = fp8x4_to_f32x4(p1.y);
        f32x4 l2 = fp8x4_to_f32x4(p2.x), h2 = fp8x4_to_f32x4(p2.y);
        f32x4 l3 = fp8x4_to_f32x4(p3.x), h3 = fp8x4_to_f32x4(p3.y);
        A += (l0 + l1) + (l2 + l3);
        B += (h0 + h1) + (h2 + h3);
        id = idn;
    }
    if (g == 0) {
        A += fp8x4_to_f32x4(sp.x);
        B += fp8x4_to_f32x4(sp.y);
    }
    // reduce the 4 edge-groups: lanes c8, c8+16, c8+32, c8+48
    #pragma unroll
    for (int off = 32; off >= 16; off >>= 1) {
        A.x += __shfl_down(A.x, off, 64);
        A.y += __shfl_down(A.y, off, 64);
        A.z += __shfl_down(A.z, off, 64);
        A.w += __shfl_down(A.w, off, 64);
        B.x += __shfl_down(B.x, off, 64);
        B.y += __shfl_down(B.y, off, 64);
        B.z += __shfl_down(B.z, off, 64);
        B.w += __shfl_down(B.w, off, 64);
    }
    if (g == 0) {
        uint4 ov;
        ov.x = pack_bf2(A.x, A.y);
        ov.y = pack_bf2(A.z, A.w);
        ov.z = pack_bf2(B.x, B.y);
        ov.w = pack_bf2(B.z, B.w);
        *(uint4*)&Ubf[(size_t)n * 64 + c8 * 4] = ov;
    }
}

// ---------------- MFMA GEMM: mode 1 = write fp8 mirror; mode 2 = fused pool --
__global__ __launch_bounds__(256) void k_gemm_mfma(
    const uint* __restrict__ Ubf, const uint* __restrict__ Wpk,
    const float* __restrict__ gamma, const float* __restrict__ beta,
    const float* __restrict__ mean, const float* __restrict__ var,
    unsigned char* __restrict__ Hf8,
    const int* __restrict__ batch, const float* __restrict__ Wfc,
    float* __restrict__ Gz, int mode) {
    __shared__ uint lds_u[64 * 68];
    __shared__ float wfc[128];
    __shared__ int bb[64];
    __shared__ float sblk[64];
    int tid = threadIdx.x;
    int row0 = blockIdx.x * 64;
    if (mode == 2) {
        if (tid < 128) wfc[tid] = Wfc[tid];
        if (tid < 64) {
            int rr = row0 + tid;
            bb[tid] = (rr < N_NODES) ? batch[rr] : -1;
        }
    }
    #pragma unroll
    for (int it = 0; it < 4; it++) {
        int r = it * 16 + (tid >> 4);
        int c = (tid & 15) * 4;
        int gr = row0 + r; if (gr >= N_NODES) gr = N_NODES - 1;
        uint4 v = *(const uint4*)&Ubf[(size_t)gr * 64 + c];
        *(uint4*)&lds_u[r * 68 + c] = v;
    }
    __syncthreads();

    int wave = tid >> 6, lane = tid & 63;
    int m = lane & 15, quad = lane >> 4;
    bf16x8 a[4];
    #pragma unroll
    for (int kt = 0; kt < 4; kt++)
        a[kt] = *(const bf16x8*)&lds_u[(wave * 16 + m) * 68 + kt * 16 + quad * 4];

    f32x4 acc[8];
    #pragma unroll
    for (int nt = 0; nt < 8; nt++) acc[nt] = (f32x4){0.f, 0.f, 0.f, 0.f};

    #pragma unroll
    for (int nt = 0; nt < 8; nt++) {
        #pragma unroll
        for (int kt = 0; kt < 4; kt++) {
            bf16x8 b = *(const bf16x8*)&Wpk[((size_t)(kt * 8 + nt) * 64 + lane) * 4];
            acc[nt] = __builtin_amdgcn_mfma_f32_16x16x32_bf16(a[kt], b, acc[nt], 0, 0, 0);
        }
    }

    if (mode == 1) {
        #pragma unroll
        for (int nt = 0; nt < 8; nt++) {
            int col = nt * 16 + m;
            float sc = gamma[col] * rsqrtf(var[col] + EPS_BN);
            float sh = beta[col] - mean[col] * sc;
            #pragma unroll
            for (int r = 0; r < 4; r++) {
                int row = row0 + wave * 16 + quad * 4 + r;
                if (row < N_NODES) {
                    float z = fmaxf(acc[nt][r] * sc + sh, 0.0f);
                    Hf8[(size_t)row * 128 + col] = f32_to_fp8(z);
                }
            }
        }
    } else {
        float pr[4] = {0.f, 0.f, 0.f, 0.f};
        #pragma unroll
        for (int nt = 0; nt < 8; nt++) {
            int col = nt * 16 + m;
            float sc = gamma[col] * rsqrtf(var[col] + EPS_BN);
            float sh = beta[col] - mean[col] * sc;
            float wf = wfc[col];
            #pragma unroll
            for (int r = 0; r < 4; r++) {
                float z = fmaxf(acc[nt][r] * sc + sh, 0.0f);
                pr[r] += z * wf;
            }
        }
        #pragma unroll
        for (int r = 0; r < 4; r++) {
            float p = pr[r];
            p += __shfl_down(p, 8, 16);
            p += __shfl_down(p, 4, 16);
            p += __shfl_down(p, 2, 16);
            p += __shfl_down(p, 1, 16);
            if (m == 0) sblk[wave * 16 + quad * 4 + r] = p;
        }
        __syncthreads();
        if (tid == 0) {
            int i = 0;
            while (i < 64 && row0 + i < N_NODES) {
                int g = bb[i];
                float s = 0.0f;
                while (i < 64 && row0 + i < N_NODES && bb[i] == g) {
                    s += sblk[i]; i++;
                }
                atomicAdd(&Gz[g], s);
            }
        }
    }
}

// ---------------- final: out[g] = sigmoid(Gz[g] / count) ---------------------
__global__ void k_fc(const float* __restrict__ Gz, const int* __restrict__ gstart,
                     float* __restrict__ out) {
    int g = threadIdx.x;
    if (g < N_GRAPHS) {
        int c = gstart[g + 1] - gstart[g];
        float z = Gz[g] / fmaxf((float)c, 1.0f);
        out[g] = 1.0f / (1.0f + expf(-z));
    }
}

extern "C" void kernel_launch(void* const* d_in, const int* in_sizes, int n_in,
                              void* d_out, int out_size, void* d_ws, size_t ws_size,
                              hipStream_t stream) {
    const float* x     = (const float*)d_in[0];
    const int*   ei    = (const int*)d_in[1];
    const int*   batch = (const int*)d_in[2];
    const float* W1    = (const float*)d_in[3];
    const float* g1    = (const float*)d_in[4];
    const float* b1    = (const float*)d_in[5];
    const float* m1    = (const float*)d_in[6];
    const float* v1    = (const float*)d_in[7];
    const float* W2    = (const float*)d_in[8];
    const float* g2    = (const float*)d_in[9];
    const float* b2    = (const float*)d_in[10];
    const float* m2    = (const float*)d_in[11];
    const float* v2    = (const float*)d_in[12];
    const float* W3    = (const float*)d_in[13];
    const float* g3    = (const float*)d_in[14];
    const float* b3    = (const float*)d_in[15];
    const float* m3    = (const float*)d_in[16];
    const float* v3    = (const float*)d_in[17];
    const float* Wfc   = (const float*)d_in[18];
    float* out = (float*)d_out;

    const int* srcp = ei;
    const int* dstp = ei + N_EDGES;

    // workspace carve (identical to round 2)
    uint* Ubf  = (uint*)d_ws;                           // N*64 uints; doubles as ebuf
    uint* Hf8u = Ubf + (size_t)N_NODES * 64;            // N*32 + 32 (sentinel row)
    int* cnt   = (int*)(Hf8u + (size_t)N_NODES * 32 + 32);  // N
    int* ell   = cnt + N_NODES;                         // N*ELLW (25.6 MB)
    int* gstart = ell + (size_t)N_NODES * ELLW;         // pad 260
    ushort* Wpk2 = (ushort*)(gstart + 260);             // 16384 shorts
    ushort* Wpk3 = Wpk2 + 16384;                        // 16384 shorts
    int* hist  = (int*)(Wpk3 + 16384);                  // BLD_NBLK*P_PART
    int* offs  = hist + BLD_NBLK * P_PART;              // BLD_NBLK*P_PART
    int* parr  = offs + BLD_NBLK * P_PART;              // P_PART+1 (pad 400)
    int* tot   = parr + 400;                            // P_PART (pad 400)
    float* Gz  = (float*)(tot + 400);                   // N_GRAPHS
    i32x2* ebuf = (i32x2*)Ubf;                          // N_EDGES int2 (12.8 MB)
    uint* Hf8pad = Hf8u + (size_t)N_NODES * 32;         // zero sentinel row

    // sorted ELL build (no global atomics) + fused prep + Gz/sentinel zero
    k_hist<<<609, 256, 0, stream>>>(dstp, hist, batch, gstart, W2, Wpk2, W3, Wpk3,
                                    Gz, Hf8pad);
    k_scan_a<<<P_PART, 256, 0, stream>>>(hist, offs, tot);
    k_scan_b<<<1, 512, 0, stream>>>(tot, parr);
    k_scatter<<<BLD_NBLK, 256, 0, stream>>>(srcp, dstp, offs, parr, ebuf);
    k_build<<<P_PART, 256, 0, stream>>>(ebuf, parr, cnt, ell);

    // layer 1 (fused aggregate + MLP; fp8 mirror only)
    k_layer1<<<(N_NODES + 15) / 16, 256, 0, stream>>>(
        x, cnt, ell, W1, g1, b1, m1, v1, Hf8u);
    // layer 2
    k_aggr128<<<(N_NODES * 64 + 255) / 256, 256, 0, stream>>>(Hf8u, cnt, ell, Ubf);
    k_gemm_mfma<<<(N_NODES + 63) / 64, 256, 0, stream>>>(
        Ubf, (const uint*)Wpk2, g2, b2, m2, v2, (unsigned char*)Hf8u,
        batch, Wfc, Gz, 1);
    // layer 3 (+ fused pooling)
    k_aggr128<<<(N_NODES * 64 + 255) / 256, 256, 0, stream>>>(Hf8u, cnt, ell, Ubf);
    k_gemm_mfma<<<(N_NODES + 63) / 64, 256, 0, stream>>>(
        Ubf, (const uint*)Wpk3, g3, b3, m3, v3, (unsigned char*)Hf8u,
        batch, Wfc, Gz, 2);
    // final sigmoid
    k_fc<<<1, 256, 0, stream>>>(Gz, gstart, out);
}

// Round 9
// 270.605 us; speedup vs baseline: 1.3038x; 1.0157x over previous
//
#include <hip/hip_runtime.h>
#include <hip/hip_fp8.h>
#include <math.h>

#define N_NODES 100000
#define N_EDGES 1600000
#define N_GRAPHS 256
#define H 128
#define EPS_BN 1e-5f
#define ELLW 64

// sort-based build params
#define PSZ 256
#define PSH 8
#define P_PART 391                    // ceil(100000/256)
#define NB_BLD 782                    // hist/scatter blocks (8 edges/thread)
#define EPT_B 8
#define EPB_B (256 * EPT_B)           // 2048 edges per block

typedef unsigned int uint;
typedef unsigned short ushort;
typedef __attribute__((ext_vector_type(8))) short bf16x8;
typedef __attribute__((ext_vector_type(4))) float f32x4;
typedef __attribute__((ext_vector_type(2))) float f32x2;
typedef __attribute__((ext_vector_type(4))) int i32x4;

// ---- bf16 helpers ----
__device__ __forceinline__ uint f2bf_bits(float x) {
    uint u = __float_as_uint(x);
    return (u + 0x7fffu + ((u >> 16) & 1u)) >> 16;
}
__device__ __forceinline__ uint pack_bf2(float a, float b) {
    return f2bf_bits(a) | (f2bf_bits(b) << 16);
}

// ---- fp8 helpers ----
__device__ __forceinline__ unsigned char f32_to_fp8(float x) {
#if __has_builtin(__builtin_amdgcn_cvt_pk_fp8_f32)
    int v = __builtin_amdgcn_cvt_pk_fp8_f32(x, 0.0f, 0, false);
    return (unsigned char)(v & 0xff);
#else
    __hip_fp8_e4m3 q(x);
    return (unsigned char)q.__x;
#endif
}
__device__ __forceinline__ f32x4 fp8x4_to_f32x4(uint v) {
    f32x4 r;
#if __has_builtin(__builtin_amdgcn_cvt_pk_f32_fp8)
    f32x2 lo = __builtin_amdgcn_cvt_pk_f32_fp8((int)v, false);
    f32x2 hi = __builtin_amdgcn_cvt_pk_f32_fp8((int)v, true);
    r.x = lo.x; r.y = lo.y; r.z = hi.x; r.w = hi.y;
#else
    __hip_fp8_e4m3 a, b, c, d;
    a.__x = (unsigned char)(v & 0xff);
    b.__x = (unsigned char)((v >> 8) & 0xff);
    c.__x = (unsigned char)((v >> 16) & 0xff);
    d.__x = (unsigned char)((v >> 24) & 0xff);
    r.x = (float)a; r.y = (float)b; r.z = (float)c; r.w = (float)d;
#endif
    return r;
}

// ====== fused: histogram (0..781) + graph bounds (782..1173) + W packs
//        (1174..1189) + Gz zero + Hf8 sentinel-row zero (1190) ===============
__global__ __launch_bounds__(256) void k_hist(const int* __restrict__ dst,
                                              int* __restrict__ hist,
                                              const int* __restrict__ batch,
                                              int* __restrict__ gstart,
                                              const float* __restrict__ W2,
                                              ushort* __restrict__ Wpk2,
                                              const float* __restrict__ W3,
                                              ushort* __restrict__ Wpk3,
                                              float* __restrict__ Gz,
                                              uint* __restrict__ Hf8pad) {
    __shared__ int h[P_PART];
    int b = blockIdx.x;
    if (b < NB_BLD) {
        for (int i = threadIdx.x; i < P_PART; i += 256) h[i] = 0;
        __syncthreads();
        int base = b * EPB_B + threadIdx.x * EPT_B;
        #pragma unroll
        for (int j = 0; j < EPT_B / 4; j++) {
            int e = base + j * 4;
            if (e + 4 <= N_EDGES) {
                i32x4 d = __builtin_nontemporal_load((const i32x4*)&dst[e]);
                atomicAdd(&h[d.x >> PSH], 1);
                atomicAdd(&h[d.y >> PSH], 1);
                atomicAdd(&h[d.z >> PSH], 1);
                atomicAdd(&h[d.w >> PSH], 1);
            }
        }
        __syncthreads();
        for (int i = threadIdx.x; i < P_PART; i += 256)
            hist[b * P_PART + i] = h[i];
        return;
    }
    if (b < 1174) {
        int n = (b - NB_BLD) * 256 + threadIdx.x;
        if (n >= N_NODES) return;
        int g = batch[n];
        int gp = (n == 0) ? -1 : batch[n - 1];
        for (int gr = gp + 1; gr <= g; gr++) gstart[gr] = n;
        if (n == N_NODES - 1) {
            for (int gr = g + 1; gr <= N_GRAPHS; gr++) gstart[gr] = N_NODES;
        }
        return;
    }
    if (b >= 1190) {
        if (threadIdx.x < N_GRAPHS) Gz[threadIdx.x] = 0.0f;
        if (threadIdx.x < 32) Hf8pad[threadIdx.x] = 0u;   // zero sentinel row
        return;
    }
    const float* W = (b < 1182) ? W2 : W3;
    ushort* Wpk = (b < 1182) ? Wpk2 : Wpk3;
    int t = ((b < 1182) ? (b - 1174) : (b - 1182)) * 256 + threadIdx.x;  // 0..2047
    int lane = t & 63, nt = (t >> 6) & 7, kt = t >> 9;
    int n = nt * 16 + (lane & 15);
    int kbase = kt * 32 + (lane >> 4) * 8;
    ushort v[8];
    #pragma unroll
    for (int j = 0; j < 8; j++)
        v[j] = (ushort)f2bf_bits(W[(size_t)(kbase + j) * H + n]);
    uint4 pk;
    pk.x = (uint)v[0] | ((uint)v[1] << 16);
    pk.y = (uint)v[2] | ((uint)v[3] << 16);
    pk.z = (uint)v[4] | ((uint)v[5] << 16);
    pk.w = (uint)v[6] | ((uint)v[7] << 16);
    *(uint4*)&Wpk[(size_t)t * 8] = pk;
}

// ---- scan A: exclusive prefix over 782 block-entries at each partition -----
// 256 threads x 4 serial entries each, then Hillis-Steele over thread totals.
__global__ __launch_bounds__(256) void k_scan_a(const int* __restrict__ hist,
                                                int* __restrict__ offs,
                                                int* __restrict__ tot) {
    __shared__ int lds[256];
    int p = blockIdx.x;
    int t = threadIdx.x;
    int v0 = 0, v1 = 0, v2 = 0, v3 = 0;
    int b0 = t * 4;
    if (b0 + 0 < NB_BLD) v0 = hist[(b0 + 0) * P_PART + p];
    if (b0 + 1 < NB_BLD) v1 = hist[(b0 + 1) * P_PART + p];
    if (b0 + 2 < NB_BLD) v2 = hist[(b0 + 2) * P_PART + p];
    if (b0 + 3 < NB_BLD) v3 = hist[(b0 + 3) * P_PART + p];
    int tt = v0 + v1 + v2 + v3;
    lds[t] = tt;
    __syncthreads();
    for (int off = 1; off < 256; off <<= 1) {
        int tmp = (t >= off) ? lds[t - off] : 0;
        __syncthreads();
        lds[t] += tmp;
        __syncthreads();
    }
    int run = lds[t] - tt;                 // exclusive prefix of this thread
    if (b0 + 0 < NB_BLD) { offs[(b0 + 0) * P_PART + p] = run; run += v0; }
    if (b0 + 1 < NB_BLD) { offs[(b0 + 1) * P_PART + p] = run; run += v1; }
    if (b0 + 2 < NB_BLD) { offs[(b0 + 2) * P_PART + p] = run; run += v2; }
    if (b0 + 3 < NB_BLD) { offs[(b0 + 3) * P_PART + p] = run; run += v3; }
    if (t == 255) tot[p] = lds[255];
}

// ---- scan B ----------------------------------------------------------------
__global__ void k_scan_b(const int* __restrict__ tot, int* __restrict__ parr) {
    __shared__ int lds[512];
    int p = threadIdx.x;
    int v = (p < P_PART) ? tot[p] : 0;
    lds[p] = v;
    __syncthreads();
    for (int off = 1; off < 512; off <<= 1) {
        int tmp = (p >= off) ? lds[p - off] : 0;
        __syncthreads();
        lds[p] += tmp;
        __syncthreads();
    }
    if (p < P_PART) parr[p] = lds[p] - v;
    if (p == 0) parr[P_PART] = N_EDGES;
}

// ---- scatter: packed ebuf entry = (src<<8) | (dst & 255) -------------------
__global__ __launch_bounds__(256) void k_scatter(const int* __restrict__ src,
                                                 const int* __restrict__ dst,
                                                 const int* __restrict__ offs,
                                                 const int* __restrict__ parr,
                                                 uint* __restrict__ ebuf) {
    __shared__ int lofs[P_PART];
    for (int i = threadIdx.x; i < P_PART; i += 256)
        lofs[i] = offs[blockIdx.x * P_PART + i] + parr[i];
    __syncthreads();
    int base = blockIdx.x * EPB_B + threadIdx.x * EPT_B;
    #pragma unroll
    for (int j = 0; j < EPT_B / 4; j++) {
        int e = base + j * 4;
        if (e + 4 <= N_EDGES) {
            i32x4 d = __builtin_nontemporal_load((const i32x4*)&dst[e]);
            i32x4 s = __builtin_nontemporal_load((const i32x4*)&src[e]);
            #pragma unroll
            for (int k = 0; k < 4; k++) {
                int dk = (k == 0) ? d.x : (k == 1) ? d.y : (k == 2) ? d.z : d.w;
                int sk = (k == 0) ? s.x : (k == 1) ? s.y : (k == 2) ? s.z : s.w;
                int pos = atomicAdd(&lofs[dk >> PSH], 1);
                ebuf[pos] = ((uint)sk << 8) | ((uint)dk & 255u);
            }
        }
    }
}

// build ELL + pad each row to a multiple of 16 with the zero-sentinel index
__global__ __launch_bounds__(256) void k_build(const uint* __restrict__ ebuf,
                                               const int* __restrict__ parr,
                                               int* __restrict__ cnt,
                                               int* __restrict__ ell) {
    __shared__ int lc[PSZ];
    int p = blockIdx.x;
    for (int i = threadIdx.x; i < PSZ; i += 256) lc[i] = 0;
    __syncthreads();
    int e0 = parr[p], e1 = parr[p + 1];
    int nb = p * PSZ;
    for (int i = e0 + threadIdx.x; i < e1; i += 256) {
        uint sd = ebuf[i];
        int dl = (int)(sd & 255u);
        int slot = atomicAdd(&lc[dl], 1);
        if (slot < ELLW) ell[(size_t)(nb + dl) * ELLW + slot] = (int)(sd >> 8);
    }
    __syncthreads();
    for (int i = threadIdx.x; i < PSZ; i += 256) {
        int n = nb + i;
        if (n < N_NODES) {
            int c = lc[i];
            cnt[n] = c;
            int cc = (c < ELLW) ? c : ELLW;
            int cp = (cc + 15) & ~15;
            if (cp > ELLW) cp = ELLW;
            for (int slot = cc; slot < cp; slot++)
                ell[(size_t)n * ELLW + slot] = N_NODES;   // sentinel (zero row)
        }
    }
}

// ---------------- fused layer 1: 4 nodes per wave, 16 lanes per node ---------
__global__ __launch_bounds__(256) void k_layer1(
    const float* __restrict__ x, const int* __restrict__ cnt,
    const int* __restrict__ ell, const float* __restrict__ W1,
    const float* __restrict__ gamma, const float* __restrict__ beta,
    const float* __restrict__ mean, const float* __restrict__ var,
    uint* __restrict__ Hf8) {
    __shared__ float scs[128], shs[128];
    int tid = threadIdx.x;
    if (tid < 128) {
        float sc = gamma[tid] * rsqrtf(var[tid] + EPS_BN);
        scs[tid] = sc;
        shs[tid] = beta[tid] - mean[tid] * sc;
    }
    __syncthreads();
    int lane = tid & 63, wave = tid >> 6;
    int sub = lane >> 4, m = lane & 15;
    int n = blockIdx.x * 16 + wave * 4 + sub;
    if (n >= N_NODES) return;
    int cn = cnt[n]; if (cn > ELLW) cn = ELLW;
    const int* row = &ell[(size_t)n * ELLW];
    const char* xb = (const char*)x;
    float4 acc = {0.f, 0.f, 0.f, 0.f};
    for (int e = m; e < cn; e += 16) {
        float4 v = *(const float4*)(xb + ((uint)row[e] << 4));
        acc.x += v.x; acc.y += v.y; acc.z += v.z; acc.w += v.w;
    }
    #pragma unroll
    for (int off = 8; off > 0; off >>= 1) {
        acc.x += __shfl_down(acc.x, off, 16);
        acc.y += __shfl_down(acc.y, off, 16);
        acc.z += __shfl_down(acc.z, off, 16);
        acc.w += __shfl_down(acc.w, off, 16);
    }
    int src = lane & 48;
    float4 xs = *(const float4*)(xb + ((uint)n << 4));
    float uu[4];
    uu[0] = __shfl(acc.x, src, 64) + xs.x;
    uu[1] = __shfl(acc.y, src, 64) + xs.y;
    uu[2] = __shfl(acc.z, src, 64) + xs.z;
    uu[3] = __shfl(acc.w, src, 64) + xs.w;
    int j0 = m * 8;
    float z[8] = {0.f, 0.f, 0.f, 0.f, 0.f, 0.f, 0.f, 0.f};
    #pragma unroll
    for (int k = 0; k < 4; k++) {
        float4 wa = *(const float4*)&W1[k * H + j0];
        float4 wb = *(const float4*)&W1[k * H + j0 + 4];
        z[0] += uu[k] * wa.x; z[1] += uu[k] * wa.y;
        z[2] += uu[k] * wa.z; z[3] += uu[k] * wa.w;
        z[4] += uu[k] * wb.x; z[5] += uu[k] * wb.y;
        z[6] += uu[k] * wb.z; z[7] += uu[k] * wb.w;
    }
    #pragma unroll
    for (int i = 0; i < 8; i++)
        z[i] = fmaxf(z[i] * scs[j0 + i] + shs[j0 + i], 0.0f);
    uint2 q;
    q.x = (uint)f32_to_fp8(z[0]) | ((uint)f32_to_fp8(z[1]) << 8)
        | ((uint)f32_to_fp8(z[2]) << 16) | ((uint)f32_to_fp8(z[3]) << 24);
    q.y = (uint)f32_to_fp8(z[4]) | ((uint)f32_to_fp8(z[5]) << 8)
        | ((uint)f32_to_fp8(z[6]) << 16) | ((uint)f32_to_fp8(z[7]) << 24);
    *(uint2*)&Hf8[(size_t)n * 32 + m * 2] = q;
}

// ---------------- H=128 aggregation, one node per wave ----------------------
// 16 lanes x uint2 cover the 128B row (4 rows per wave-instruction);
// 4 edge-groups (lane>>4) each gather 4 consecutive edges per 16-edge block.
// ELL rows padded to x16 with the zero-sentinel row -> uniform loop.
// 32-bit byte-offset addressing: base + (s<<7 | c8<<3).
__global__ __launch_bounds__(256) void k_aggr128(
    const uint* __restrict__ Hf8, const int* __restrict__ cnt,
    const int* __restrict__ ell, uint* __restrict__ Ubf) {
    int t = blockIdx.x * 256 + threadIdx.x;
    int n = t >> 6, lane = t & 63;
    if (n >= N_NODES) return;
    int g = lane >> 4, c8 = lane & 15;
    const int* row = &ell[(size_t)n * ELLW];
    const char* Hb = (const char*)Hf8;
    uint co = (uint)c8 << 3;                 // byte offset within row
    i32x4 id = *(const i32x4*)(row + 4 * g);
    uint2 sp = {0u, 0u};
    if (g == 0) sp = *(const uint2*)(Hb + (((uint)n << 7) | co));
    int cn = cnt[n]; if (cn > ELLW) cn = ELLW;
    int cnp = (cn + 15) & ~15; if (cnp > ELLW) cnp = ELLW;

    f32x4 A = {0.f, 0.f, 0.f, 0.f};
    f32x4 B = {0.f, 0.f, 0.f, 0.f};
    for (int e = 0; e < cnp; e += 16) {
        i32x4 idn = id;
        if (e + 16 < cnp) idn = *(const i32x4*)(row + e + 16 + 4 * g);
        uint2 p0 = *(const uint2*)(Hb + (((uint)id.x << 7) | co));
        uint2 p1 = *(const uint2*)(Hb + (((uint)id.y << 7) | co));
        uint2 p2 = *(const uint2*)(Hb + (((uint)id.z << 7) | co));
        uint2 p3 = *(const uint2*)(Hb + (((uint)id.w << 7) | co));
        f32x4 l0 = fp8x4_to_f32x4(p0.x), h0 = fp8x4_to_f32x4(p0.y);
        f32x4 l1 = fp8x4_to_f32x4(p1.x), h1 = fp8x4_to_f32x4(p1.y);
        f32x4 l2 = fp8x4_to_f32x4(p2.x), h2 = fp8x4_to_f32x4(p2.y);
        f32x4 l3 = fp8x4_to_f32x4(p3.x), h3 = fp8x4_to_f32x4(p3.y);
        A += (l0 + l1) + (l2 + l3);
        B += (h0 + h1) + (h2 + h3);
        id = idn;
    }
    if (g == 0) {
        A += fp8x4_to_f32x4(sp.x);
        B += fp8x4_to_f32x4(sp.y);
    }
    #pragma unroll
    for (int off = 32; off >= 16; off >>= 1) {
        A.x += __shfl_down(A.x, off, 64);
        A.y += __shfl_down(A.y, off, 64);
        A.z += __shfl_down(A.z, off, 64);
        A.w += __shfl_down(A.w, off, 64);
        B.x += __shfl_down(B.x, off, 64);
        B.y += __shfl_down(B.y, off, 64);
        B.z += __shfl_down(B.z, off, 64);
        B.w += __shfl_down(B.w, off, 64);
    }
    if (g == 0) {
        uint4 ov;
        ov.x = pack_bf2(A.x, A.y);
        ov.y = pack_bf2(A.z, A.w);
        ov.z = pack_bf2(B.x, B.y);
        ov.w = pack_bf2(B.z, B.w);
        *(uint4*)&Ubf[(size_t)n * 64 + c8 * 4] = ov;
    }
}

// ---------------- MFMA GEMM: mode 1 = write fp8 mirror; mode 2 = fused pool --
__global__ __launch_bounds__(256) void k_gemm_mfma(
    const uint* __restrict__ Ubf, const uint* __restrict__ Wpk,
    const float* __restrict__ gamma, const float* __restrict__ beta,
    const float* __restrict__ mean, const float* __restrict__ var,
    unsigned char* __restrict__ Hf8,
    const int* __restrict__ batch, const float* __restrict__ Wfc,
    float* __restrict__ Gz, int mode) {
    __shared__ uint lds_u[64 * 68];
    __shared__ float sc_s[128], sh_s[128];
    __shared__ float wfc[128];
    __shared__ int bb[64];
    __shared__ float sblk[64];
    int tid = threadIdx.x;
    int row0 = blockIdx.x * 64;
    if (tid < 128) {
        float sc = gamma[tid] * rsqrtf(var[tid] + EPS_BN);
        sc_s[tid] = sc;
        sh_s[tid] = beta[tid] - mean[tid] * sc;
    }
    if (mode == 2) {
        if (tid < 128) wfc[tid] = Wfc[tid];
        if (tid < 64) {
            int rr = row0 + tid;
            bb[tid] = (rr < N_NODES) ? batch[rr] : -1;
        }
    }
    #pragma unroll
    for (int it = 0; it < 4; it++) {
        int r = it * 16 + (tid >> 4);
        int c = (tid & 15) * 4;
        int gr = row0 + r; if (gr >= N_NODES) gr = N_NODES - 1;
        uint4 v = *(const uint4*)&Ubf[(size_t)gr * 64 + c];
        *(uint4*)&lds_u[r * 68 + c] = v;
    }
    __syncthreads();

    int wave = tid >> 6, lane = tid & 63;
    int m = lane & 15, quad = lane >> 4;
    bf16x8 a[4];
    #pragma unroll
    for (int kt = 0; kt < 4; kt++)
        a[kt] = *(const bf16x8*)&lds_u[(wave * 16 + m) * 68 + kt * 16 + quad * 4];

    f32x4 acc[8];
    #pragma unroll
    for (int nt = 0; nt < 8; nt++) acc[nt] = (f32x4){0.f, 0.f, 0.f, 0.f};

    #pragma unroll
    for (int nt = 0; nt < 8; nt++) {
        #pragma unroll
        for (int kt = 0; kt < 4; kt++) {
            bf16x8 b = *(const bf16x8*)&Wpk[((size_t)(kt * 8 + nt) * 64 + lane) * 4];
            acc[nt] = __builtin_amdgcn_mfma_f32_16x16x32_bf16(a[kt], b, acc[nt], 0, 0, 0);
        }
    }

    if (mode == 1) {
        #pragma unroll
        for (int nt = 0; nt < 8; nt++) {
            int col = nt * 16 + m;
            float sc = sc_s[col], sh = sh_s[col];
            #pragma unroll
            for (int r = 0; r < 4; r++) {
                int row = row0 + wave * 16 + quad * 4 + r;
                if (row < N_NODES) {
                    float z = fmaxf(acc[nt][r] * sc + sh, 0.0f);
                    Hf8[(size_t)row * 128 + col] = f32_to_fp8(z);
                }
            }
        }
    } else {
        float pr[4] = {0.f, 0.f, 0.f, 0.f};
        #pragma unroll
        for (int nt = 0; nt < 8; nt++) {
            int col = nt * 16 + m;
            float sc = sc_s[col], sh = sh_s[col];
            float wf = wfc[col];
            #pragma unroll
            for (int r = 0; r < 4; r++) {
                float z = fmaxf(acc[nt][r] * sc + sh, 0.0f);
                pr[r] += z * wf;
            }
        }
        #pragma unroll
        for (int r = 0; r < 4; r++) {
            float p = pr[r];
            p += __shfl_down(p, 8, 16);
            p += __shfl_down(p, 4, 16);
            p += __shfl_down(p, 2, 16);
            p += __shfl_down(p, 1, 16);
            if (m == 0) sblk[wave * 16 + quad * 4 + r] = p;
        }
        __syncthreads();
        if (tid == 0) {
            int i = 0;
            while (i < 64 && row0 + i < N_NODES) {
                int g = bb[i];
                float s = 0.0f;
                while (i < 64 && row0 + i < N_NODES && bb[i] == g) {
                    s += sblk[i]; i++;
                }
                atomicAdd(&Gz[g], s);
            }
        }
    }
}

// ---------------- final: out[g] = sigmoid(Gz[g] / count) ---------------------
__global__ void k_fc(const float* __restrict__ Gz, const int* __restrict__ gstart,
                     float* __restrict__ out) {
    int g = threadIdx.x;
    if (g < N_GRAPHS) {
        int c = gstart[g + 1] - gstart[g];
        float z = Gz[g] / fmaxf((float)c, 1.0f);
        out[g] = 1.0f / (1.0f + expf(-z));
    }
}

extern "C" void kernel_launch(void* const* d_in, const int* in_sizes, int n_in,
                              void* d_out, int out_size, void* d_ws, size_t ws_size,
                              hipStream_t stream) {
    const float* x     = (const float*)d_in[0];
    const int*   ei    = (const int*)d_in[1];
    const int*   batch = (const int*)d_in[2];
    const float* W1    = (const float*)d_in[3];
    const float* g1    = (const float*)d_in[4];
    const float* b1    = (const float*)d_in[5];
    const float* m1    = (const float*)d_in[6];
    const float* v1    = (const float*)d_in[7];
    const float* W2    = (const float*)d_in[8];
    const float* g2    = (const float*)d_in[9];
    const float* b2    = (const float*)d_in[10];
    const float* m2    = (const float*)d_in[11];
    const float* v2    = (const float*)d_in[12];
    const float* W3    = (const float*)d_in[13];
    const float* g3    = (const float*)d_in[14];
    const float* b3    = (const float*)d_in[15];
    const float* m3    = (const float*)d_in[16];
    const float* v3    = (const float*)d_in[17];
    const float* Wfc   = (const float*)d_in[18];
    float* out = (float*)d_out;

    const int* srcp = ei;
    const int* dstp = ei + N_EDGES;

    // workspace carve
    uint* Ubf  = (uint*)d_ws;                           // N*64 uints; doubles as ebuf
    uint* Hf8u = Ubf + (size_t)N_NODES * 64;            // N*32 + 32 (sentinel row)
    int* cnt   = (int*)(Hf8u + (size_t)N_NODES * 32 + 32);  // N
    int* ell   = cnt + N_NODES;                         // N*ELLW (25.6 MB)
    int* gstart = ell + (size_t)N_NODES * ELLW;         // pad 260
    ushort* Wpk2 = (ushort*)(gstart + 260);             // 16384 shorts
    ushort* Wpk3 = Wpk2 + 16384;                        // 16384 shorts
    int* hist  = (int*)(Wpk3 + 16384);                  // NB_BLD*P_PART (1.22MB)
    int* offs  = hist + NB_BLD * P_PART;                // NB_BLD*P_PART
    int* parr  = offs + NB_BLD * P_PART;                // P_PART+1 (pad 400)
    int* tot   = parr + 400;                            // P_PART (pad 400)
    float* Gz  = (float*)(tot + 400);                   // N_GRAPHS
    uint* ebuf = Ubf;                                   // N_EDGES uints (6.4 MB)
    uint* Hf8pad = Hf8u + (size_t)N_NODES * 32;         // zero sentinel row

    // sorted ELL build (no global atomics) + fused prep + Gz/sentinel zero
    k_hist<<<1191, 256, 0, stream>>>(dstp, hist, batch, gstart, W2, Wpk2, W3, Wpk3,
                                     Gz, Hf8pad);
    k_scan_a<<<P_PART, 256, 0, stream>>>(hist, offs, tot);
    k_scan_b<<<1, 512, 0, stream>>>(tot, parr);
    k_scatter<<<NB_BLD, 256, 0, stream>>>(srcp, dstp, offs, parr, ebuf);
    k_build<<<P_PART, 256, 0, stream>>>(ebuf, parr, cnt, ell);

    // layer 1 (fused aggregate + MLP; fp8 mirror only)
    k_layer1<<<(N_NODES + 15) / 16, 256, 0, stream>>>(
        x, cnt, ell, W1, g1, b1, m1, v1, Hf8u);
    // layer 2
    k_aggr128<<<(N_NODES * 64 + 255) / 256, 256, 0, stream>>>(Hf8u, cnt, ell, Ubf);
    k_gemm_mfma<<<(N_NODES + 63) / 64, 256, 0, stream>>>(
        Ubf, (const uint*)Wpk2, g2, b2, m2, v2, (unsigned char*)Hf8u,
        batch, Wfc, Gz, 1);
    // layer 3 (+ fused pooling)
    k_aggr128<<<(N_NODES * 64 + 255) / 256, 256, 0, stream>>>(Hf8u, cnt, ell, Ubf);
    k_gemm_mfma<<<(N_NODES + 63) / 64, 256, 0, stream>>>(
        Ubf, (const uint*)Wpk3, g3, b3, m3, v3, (unsigned char*)Hf8u,
        batch, Wfc, Gz, 2);
    // final sigmoid
    k_fc<<<1, 256, 0, stream>>>(Gz, gstart, out);
}